// Round 1
// baseline (565.309 us; speedup 1.0000x reference)
//
#include <hip/hip_runtime.h>
#include <hip/hip_bf16.h>

#define T_SEQ 2048
#define E_DIM 2048
#define D_HEAD 64
#define B_SZ 4
#define NROWS (B_SZ * T_SEQ)  // 8192 flattened (b,t) rows

// ---------------------------------------------------------------------------
// Projection: dst[r][o] = sum_e x[r][e] * W[o][e] + bias[o]
// BM=64 rows x BN=64 outs per block, BK=32, one projection per blockIdx.y.
// W tile stored transposed in LDS (wt[k][n]) so compute-side b128 reads are
// ~2-way bank-aliased (free); x tile [m][k] with stride 36 (16B-aligned rows).
// ---------------------------------------------------------------------------
__global__ __launch_bounds__(256) void proj_kernel(
    const float* __restrict__ x,
    const float* __restrict__ Wq, const float* __restrict__ bq,
    const float* __restrict__ Wk, const float* __restrict__ bk,
    const float* __restrict__ Wv, const float* __restrict__ bv,
    float* __restrict__ qb, float* __restrict__ kb, float* __restrict__ vb)
{
    const int py = blockIdx.y;
    const float* __restrict__ W    = (py == 0) ? Wq : (py == 1) ? Wk : Wv;
    const float* __restrict__ bias = (py == 0) ? bq : (py == 1) ? bk : bv;
    float* __restrict__ dst        = (py == 0) ? qb : (py == 1) ? kb : vb;

    __shared__ float xs[64][36];   // [m][k], stride 36 floats = 144B (16B-aligned)
    __shared__ float wt[32][68];   // [k][n] transposed, stride 68 floats = 272B

    const int tid  = threadIdx.x;
    const int row0 = blockIdx.x * 64;
    const int lrow = tid >> 3;          // 0..31
    const int lk4  = (tid & 7) << 2;    // 0,4,...,28
    const int tm   = tid >> 4;          // 0..15 -> rows tm*4..tm*4+3
    const int tn   = tid & 15;          // 0..15 -> cols tn*4..tn*4+3

    float acc[4][4] = {};

    for (int k0 = 0; k0 < E_DIM; k0 += 32) {
        // issue global loads before the barrier (overlap with prev compute)
        float4 a0 = *(const float4*)(x + (size_t)(row0 + lrow) * E_DIM + k0 + lk4);
        float4 a1 = *(const float4*)(x + (size_t)(row0 + lrow + 32) * E_DIM + k0 + lk4);
        float4 w0 = *(const float4*)(W + (size_t)lrow * E_DIM + k0 + lk4);
        float4 w1 = *(const float4*)(W + (size_t)(lrow + 32) * E_DIM + k0 + lk4);
        __syncthreads();  // previous iteration's compute done before overwrite
        *(float4*)&xs[lrow][lk4]      = a0;
        *(float4*)&xs[lrow + 32][lk4] = a1;
        wt[lk4 + 0][lrow] = w0.x; wt[lk4 + 1][lrow] = w0.y;
        wt[lk4 + 2][lrow] = w0.z; wt[lk4 + 3][lrow] = w0.w;
        wt[lk4 + 0][lrow + 32] = w1.x; wt[lk4 + 1][lrow + 32] = w1.y;
        wt[lk4 + 2][lrow + 32] = w1.z; wt[lk4 + 3][lrow + 32] = w1.w;
        __syncthreads();

        #pragma unroll
        for (int kq = 0; kq < 8; ++kq) {
            float xa[4][4], wb[4][4];
            #pragma unroll
            for (int mi = 0; mi < 4; ++mi)
                *(float4*)&xa[mi][0] = *(const float4*)&xs[tm * 4 + mi][kq * 4];
            #pragma unroll
            for (int j = 0; j < 4; ++j)
                *(float4*)&wb[j][0] = *(const float4*)&wt[kq * 4 + j][tn * 4];
            #pragma unroll
            for (int mi = 0; mi < 4; ++mi)
                #pragma unroll
                for (int ni = 0; ni < 4; ++ni)
                    #pragma unroll
                    for (int j = 0; j < 4; ++j)
                        acc[mi][ni] = fmaf(xa[mi][j], wb[j][ni], acc[mi][ni]);
        }
    }

    #pragma unroll
    for (int mi = 0; mi < 4; ++mi)
        #pragma unroll
        for (int ni = 0; ni < 4; ++ni)
            dst[(size_t)(row0 + tm * 4 + mi) * D_HEAD + tn * 4 + ni] =
                acc[mi][ni] + bias[tn * 4 + ni];
}

// ---------------------------------------------------------------------------
// Attention: one block of 256 threads per query row (b,t).
// Phase 1: logits[s] for s<=t (causal implicit), q cached in registers.
// Phase 2: block-tree max / exp / sum.
// Phase 3: PV with (d = tid&63, g = tid>>6) -> coalesced V row reads per wave.
// ---------------------------------------------------------------------------
__global__ __launch_bounds__(256) void attn_kernel(
    const float* __restrict__ qb, const float* __restrict__ kb,
    const float* __restrict__ vb, float* __restrict__ out)
{
    __shared__ float q_s[D_HEAD];
    __shared__ float lg[T_SEQ];
    __shared__ float red[256];

    const int tid = threadIdx.x;
    const int t   = blockIdx.x & (T_SEQ - 1);
    const int b   = blockIdx.x >> 11;       // T=2048=2^11
    const size_t base = (size_t)b * T_SEQ;

    if (tid < D_HEAD) q_s[tid] = qb[(base + t) * D_HEAD + tid];
    __syncthreads();

    // cache q in registers (16 float4 = 64 VGPR)
    float4 qv[16];
    #pragma unroll
    for (int j = 0; j < 16; ++j) qv[j] = ((const float4*)q_s)[j];

    // phase 1: logits
    for (int s = tid; s <= t; s += 256) {
        const float4* kr = (const float4*)(kb + (base + s) * D_HEAD);
        float a = 0.f;
        #pragma unroll
        for (int j = 0; j < 16; ++j) {
            float4 kv = kr[j];
            a += qv[j].x * kv.x + qv[j].y * kv.y + qv[j].z * kv.z + qv[j].w * kv.w;
        }
        lg[s] = a * 0.125f;   // 1/sqrt(64)
    }
    __syncthreads();

    // phase 2a: max
    float lm = -3.0e38f;
    for (int s = tid; s <= t; s += 256) lm = fmaxf(lm, lg[s]);
    red[tid] = lm;
    __syncthreads();
    for (int off = 128; off > 0; off >>= 1) {
        if (tid < off) red[tid] = fmaxf(red[tid], red[tid + off]);
        __syncthreads();
    }
    const float m = red[0];
    __syncthreads();

    // phase 2b: exp + sum
    float ls = 0.f;
    for (int s = tid; s <= t; s += 256) {
        float e = __expf(lg[s] - m);
        lg[s] = e;
        ls += e;
    }
    red[tid] = ls;
    __syncthreads();
    for (int off = 128; off > 0; off >>= 1) {
        if (tid < off) red[tid] += red[tid + off];
        __syncthreads();
    }
    const float inv = 1.0f / red[0];
    __syncthreads();

    // phase 3: PV
    const int d = tid & 63;
    const int g = tid >> 6;
    float a = 0.f;
    for (int s = g; s <= t; s += 4)
        a = fmaf(lg[s], vb[(base + s) * D_HEAD + d], a);
    red[tid] = a;
    __syncthreads();
    if (g == 0)
        out[(base + t) * D_HEAD + d] =
            (red[d] + red[64 + d] + red[128 + d] + red[192 + d]) * inv;
}

extern "C" void kernel_launch(void* const* d_in, const int* in_sizes, int n_in,
                              void* d_out, int out_size, void* d_ws, size_t ws_size,
                              hipStream_t stream) {
    const float* x  = (const float*)d_in[0];
    const float* Wq = (const float*)d_in[1];
    const float* bq = (const float*)d_in[2];
    const float* Wk = (const float*)d_in[3];
    const float* bk = (const float*)d_in[4];
    const float* Wv = (const float*)d_in[5];
    const float* bv = (const float*)d_in[6];
    float* out = (float*)d_out;

    // workspace: q,k,v each NROWS*64 fp32 = 2 MB -> 6 MB total
    float* qb = (float*)d_ws;
    float* kb = qb + (size_t)NROWS * D_HEAD;
    float* vb = kb + (size_t)NROWS * D_HEAD;

    dim3 pgrid(NROWS / 64, 3);
    proj_kernel<<<pgrid, 256, 0, stream>>>(x, Wq, bq, Wk, bk, Wv, bv, qb, kb, vb);
    attn_kernel<<<NROWS, 256, 0, stream>>>(qb, kb, vb, out);
}

// Round 2
// 257.216 us; speedup vs baseline: 2.1978x; 2.1978x over previous
//
#include <hip/hip_runtime.h>
#include <hip/hip_bf16.h>

#define T_SEQ 2048
#define E_DIM 2048
#define D_HEAD 64
#define B_SZ 4
#define NROWS (B_SZ * T_SEQ)  // 8192

typedef __attribute__((ext_vector_type(8))) short bf16x8;
typedef __attribute__((ext_vector_type(4))) float f32x4;
typedef __attribute__((ext_vector_type(4))) unsigned short u16x4;
typedef __attribute__((ext_vector_type(8))) unsigned short u16x8;

__device__ __forceinline__ unsigned short f2bf(float x) {
    __hip_bfloat16 h = __float2bfloat16(x);
    return *reinterpret_cast<unsigned short*>(&h);
}

// ---------------------------------------------------------------------------
// Projection: dst[r][o] = (sum_e x[r][e] * W[o][e] + bias[o]) * scale -> bf16
// q gets scale = 0.125*log2(e) (softmax scale folded, exact in later exp2).
// fp32 vector GEMM, BM=64 x BN=64, BK=32, one projection per blockIdx.y.
// ---------------------------------------------------------------------------
__global__ __launch_bounds__(256) void proj_kernel(
    const float* __restrict__ x,
    const float* __restrict__ Wq, const float* __restrict__ bq,
    const float* __restrict__ Wk, const float* __restrict__ bk,
    const float* __restrict__ Wv, const float* __restrict__ bv,
    __hip_bfloat16* __restrict__ qb, __hip_bfloat16* __restrict__ kb,
    __hip_bfloat16* __restrict__ vb)
{
    const int py = blockIdx.y;
    const float* __restrict__ W    = (py == 0) ? Wq : (py == 1) ? Wk : Wv;
    const float* __restrict__ bias = (py == 0) ? bq : (py == 1) ? bk : bv;
    __hip_bfloat16* __restrict__ dst = (py == 0) ? qb : (py == 1) ? kb : vb;
    const float scale = (py == 0) ? 0.18033688011112042f : 1.0f;  // 0.125*log2e

    __shared__ float xs[64][36];
    __shared__ float wt[32][68];

    const int tid  = threadIdx.x;
    const int row0 = blockIdx.x * 64;
    const int lrow = tid >> 3;
    const int lk4  = (tid & 7) << 2;
    const int tm   = tid >> 4;
    const int tn   = tid & 15;

    float acc[4][4] = {};

    for (int k0 = 0; k0 < E_DIM; k0 += 32) {
        float4 a0 = *(const float4*)(x + (size_t)(row0 + lrow) * E_DIM + k0 + lk4);
        float4 a1 = *(const float4*)(x + (size_t)(row0 + lrow + 32) * E_DIM + k0 + lk4);
        float4 w0 = *(const float4*)(W + (size_t)lrow * E_DIM + k0 + lk4);
        float4 w1 = *(const float4*)(W + (size_t)(lrow + 32) * E_DIM + k0 + lk4);
        __syncthreads();
        *(float4*)&xs[lrow][lk4]      = a0;
        *(float4*)&xs[lrow + 32][lk4] = a1;
        wt[lk4 + 0][lrow] = w0.x; wt[lk4 + 1][lrow] = w0.y;
        wt[lk4 + 2][lrow] = w0.z; wt[lk4 + 3][lrow] = w0.w;
        wt[lk4 + 0][lrow + 32] = w1.x; wt[lk4 + 1][lrow + 32] = w1.y;
        wt[lk4 + 2][lrow + 32] = w1.z; wt[lk4 + 3][lrow + 32] = w1.w;
        __syncthreads();

        #pragma unroll
        for (int kq = 0; kq < 8; ++kq) {
            float xa[4][4], wb[4][4];
            #pragma unroll
            for (int mi = 0; mi < 4; ++mi)
                *(float4*)&xa[mi][0] = *(const float4*)&xs[tm * 4 + mi][kq * 4];
            #pragma unroll
            for (int j = 0; j < 4; ++j)
                *(float4*)&wb[j][0] = *(const float4*)&wt[kq * 4 + j][tn * 4];
            #pragma unroll
            for (int mi = 0; mi < 4; ++mi)
                #pragma unroll
                for (int ni = 0; ni < 4; ++ni)
                    #pragma unroll
                    for (int j = 0; j < 4; ++j)
                        acc[mi][ni] = fmaf(xa[mi][j], wb[j][ni], acc[mi][ni]);
        }
    }

    #pragma unroll
    for (int mi = 0; mi < 4; ++mi)
        #pragma unroll
        for (int ni = 0; ni < 4; ++ni)
            dst[(size_t)(row0 + tm * 4 + mi) * D_HEAD + tn * 4 + ni] =
                __float2bfloat16((acc[mi][ni] + bias[tn * 4 + ni]) * scale);
}

// ---------------------------------------------------------------------------
// Flash attention, bf16 MFMA 16x16x32. Block = 128 threads = 2 waves,
// 32 q-rows per block (wave w owns rows q0+16w .. +15). s-tiles of 32.
// K staged row-major [32][72], V transposed [64][36], P bounced via [16][36].
// Online softmax in registers; logits already in log2 domain (scale in q).
// ---------------------------------------------------------------------------
#define LDK 72
#define LDV 36
#define LDP 36

__global__ __launch_bounds__(128) void attn_mfma_kernel(
    const __hip_bfloat16* __restrict__ qg, const __hip_bfloat16* __restrict__ kg,
    const __hip_bfloat16* __restrict__ vg, float* __restrict__ out)
{
    __shared__ unsigned short Kl[32 * LDK];
    __shared__ unsigned short Vt[64 * LDV];
    __shared__ unsigned short Pl[2 * 16 * LDP];

    const int tid = threadIdx.x;
    const int w   = tid >> 6;
    const int l   = tid & 63;
    const int r   = l & 15;
    const int g   = l >> 4;
    const int q0  = blockIdx.x * 32;
    const int b   = blockIdx.y;
    const size_t base = (size_t)b * T_SEQ;

    const unsigned short* qb16 = (const unsigned short*)qg;
    const unsigned short* kb16 = (const unsigned short*)kg;
    const unsigned short* vb16 = (const unsigned short*)vg;

    // Q fragments (A-operand), loaded once. Row = q0+16w+r; k = d.
    const unsigned short* qrow = qb16 + (base + q0 + 16 * w + r) * D_HEAD;
    bf16x8 qf[2];
    #pragma unroll
    for (int kk = 0; kk < 2; ++kk) {
        u16x4 lo = *(const u16x4*)(qrow + 32 * kk + 4 * g);
        u16x4 hi = *(const u16x4*)(qrow + 32 * kk + 16 + 4 * g);
        #pragma unroll
        for (int j = 0; j < 4; ++j) {
            qf[kk][j]     = (short)lo[j];
            qf[kk][4 + j] = (short)hi[j];
        }
    }

    f32x4 acc_o[4];
    #pragma unroll
    for (int dn = 0; dn < 4; ++dn) acc_o[dn] = (f32x4){0.f, 0.f, 0.f, 0.f};
    float m4[4] = {-1e30f, -1e30f, -1e30f, -1e30f};
    float l4[4] = {0.f, 0.f, 0.f, 0.f};

    unsigned short* pw = &Pl[w * 16 * LDP];
    const int ntiles = q0 / 32 + 1;

    for (int it = 0; it < ntiles; ++it) {
        const int s0 = it * 32;

        __syncthreads();  // prior tile's LDS reads done before overwrite
        for (int c = tid; c < 256; c += 128) {
            const int row = c >> 3;
            const int dc  = (c & 7) * 8;
            const size_t gb = (base + s0 + row) * D_HEAD + dc;
            u16x8 k8 = *(const u16x8*)(kb16 + gb);
            *(u16x8*)(&Kl[row * LDK + dc]) = k8;
            u16x8 v8 = *(const u16x8*)(vb16 + gb);
            #pragma unroll
            for (int i = 0; i < 8; ++i) Vt[(dc + i) * LDV + row] = v8[i];
        }
        __syncthreads();

        // ---- QK^T: S[16 x 32] per wave ----
        f32x4 s_acc[2];
        s_acc[0] = (f32x4){0.f, 0.f, 0.f, 0.f};
        s_acc[1] = (f32x4){0.f, 0.f, 0.f, 0.f};
        #pragma unroll
        for (int nt = 0; nt < 2; ++nt) {
            #pragma unroll
            for (int kk = 0; kk < 2; ++kk) {
                const unsigned short* kp = &Kl[(nt * 16 + r) * LDK + kk * 32 + 4 * g];
                u16x4 blo = *(const u16x4*)kp;
                u16x4 bhi = *(const u16x4*)(kp + 16);
                bf16x8 bf;
                #pragma unroll
                for (int j = 0; j < 4; ++j) {
                    bf[j]     = (short)blo[j];
                    bf[4 + j] = (short)bhi[j];
                }
                s_acc[nt] = __builtin_amdgcn_mfma_f32_16x16x32_bf16(qf[kk], bf, s_acc[nt], 0, 0, 0);
            }
        }

        // causal mask: only the diagonal tile needs it
        if (s0 == q0) {
            #pragma unroll
            for (int nt = 0; nt < 2; ++nt)
                #pragma unroll
                for (int j = 0; j < 4; ++j)
                    if (nt * 16 + r > 16 * w + 4 * g + j) s_acc[nt][j] = -1e30f;
        }

        // ---- online softmax (log2 domain) ----
        float tm[4];
        #pragma unroll
        for (int j = 0; j < 4; ++j) tm[j] = fmaxf(s_acc[0][j], s_acc[1][j]);
        #pragma unroll
        for (int mask = 1; mask < 16; mask <<= 1)
            #pragma unroll
            for (int j = 0; j < 4; ++j)
                tm[j] = fmaxf(tm[j], __shfl_xor(tm[j], mask));

        float p0[4], p1[4], rs[4];
        #pragma unroll
        for (int j = 0; j < 4; ++j) {
            const float mn = fmaxf(m4[j], tm[j]);
            const float sc = exp2f(m4[j] - mn);
            m4[j] = mn;
            p0[j] = exp2f(s_acc[0][j] - mn);
            p1[j] = exp2f(s_acc[1][j] - mn);
            rs[j] = p0[j] + p1[j];
            l4[j] *= sc;
            acc_o[0][j] *= sc; acc_o[1][j] *= sc;
            acc_o[2][j] *= sc; acc_o[3][j] *= sc;
        }
        #pragma unroll
        for (int mask = 1; mask < 16; mask <<= 1)
            #pragma unroll
            for (int j = 0; j < 4; ++j)
                rs[j] += __shfl_xor(rs[j], mask);
        #pragma unroll
        for (int j = 0; j < 4; ++j) l4[j] += rs[j];

        // ---- P -> LDS (C-layout -> A-layout bounce) ----
        #pragma unroll
        for (int j = 0; j < 4; ++j) {
            pw[(4 * g + j) * LDP + r]      = f2bf(p0[j]);
            pw[(4 * g + j) * LDP + 16 + r] = f2bf(p1[j]);
        }

        // ---- PV: O[16 x 64] += P[16 x 32] * V[32 x 64] ----
        u16x4 plo = *(const u16x4*)&pw[r * LDP + 4 * g];
        u16x4 phi = *(const u16x4*)&pw[r * LDP + 16 + 4 * g];
        bf16x8 pf;
        #pragma unroll
        for (int j = 0; j < 4; ++j) {
            pf[j]     = (short)plo[j];
            pf[4 + j] = (short)phi[j];
        }
        #pragma unroll
        for (int dn = 0; dn < 4; ++dn) {
            const unsigned short* vp = &Vt[(dn * 16 + r) * LDV + 4 * g];
            u16x4 vlo = *(const u16x4*)vp;
            u16x4 vhi = *(const u16x4*)(vp + 16);
            bf16x8 vf;
            #pragma unroll
            for (int j = 0; j < 4; ++j) {
                vf[j]     = (short)vlo[j];
                vf[4 + j] = (short)vhi[j];
            }
            acc_o[dn] = __builtin_amdgcn_mfma_f32_16x16x32_bf16(pf, vf, acc_o[dn], 0, 0, 0);
        }
    }

    // ---- epilogue ----
    #pragma unroll
    for (int j = 0; j < 4; ++j) {
        const float inv = 1.0f / l4[j];
        const int row = q0 + 16 * w + 4 * g + j;
        float* op = out + (base + row) * D_HEAD;
        #pragma unroll
        for (int dn = 0; dn < 4; ++dn)
            op[dn * 16 + r] = acc_o[dn][j] * inv;
    }
}

extern "C" void kernel_launch(void* const* d_in, const int* in_sizes, int n_in,
                              void* d_out, int out_size, void* d_ws, size_t ws_size,
                              hipStream_t stream) {
    const float* x  = (const float*)d_in[0];
    const float* Wq = (const float*)d_in[1];
    const float* bq = (const float*)d_in[2];
    const float* Wk = (const float*)d_in[3];
    const float* bk = (const float*)d_in[4];
    const float* Wv = (const float*)d_in[5];
    const float* bv = (const float*)d_in[6];
    float* out = (float*)d_out;

    // workspace: q,k,v bf16, 1 MB each
    __hip_bfloat16* qb = (__hip_bfloat16*)d_ws;
    __hip_bfloat16* kb = qb + (size_t)NROWS * D_HEAD;
    __hip_bfloat16* vb = kb + (size_t)NROWS * D_HEAD;

    dim3 pgrid(NROWS / 64, 3);
    proj_kernel<<<pgrid, 256, 0, stream>>>(x, Wq, bq, Wk, bk, Wv, bv, qb, kb, vb);
    dim3 agrid(T_SEQ / 32, B_SZ);
    attn_mfma_kernel<<<agrid, 128, 0, stream>>>(qb, kb, vb, out);
}

// Round 3
// 198.583 us; speedup vs baseline: 2.8467x; 1.2953x over previous
//
#include <hip/hip_runtime.h>
#include <hip/hip_bf16.h>

#define T_SEQ 2048
#define E_DIM 2048
#define D_HEAD 64
#define B_SZ 4
#define NROWS (B_SZ * T_SEQ)  // 8192

typedef __attribute__((ext_vector_type(8))) short bf16x8;
typedef __attribute__((ext_vector_type(4))) float f32x4;
typedef __attribute__((ext_vector_type(4))) unsigned short u16x4;
typedef __attribute__((ext_vector_type(8))) unsigned short u16x8;

__device__ __forceinline__ unsigned short f2bf(float x) {
    __hip_bfloat16 h = __float2bfloat16(x);
    return *reinterpret_cast<unsigned short*>(&h);
}

__device__ __forceinline__ u16x8 cvt8(float4 a, float4 b) {
    u16x8 t;
    t[0] = f2bf(a.x); t[1] = f2bf(a.y); t[2] = f2bf(a.z); t[3] = f2bf(a.w);
    t[4] = f2bf(b.x); t[5] = f2bf(b.y); t[6] = f2bf(b.z); t[7] = f2bf(b.w);
    return t;
}

// load an MFMA A/B fragment from an LDS row laid out [row][k] stride 72
__device__ __forceinline__ bf16x8 ldfrag(const unsigned short* p) {
    u16x4 lo = *(const u16x4*)p;
    u16x4 hi = *(const u16x4*)(p + 16);
    bf16x8 f;
    #pragma unroll
    for (int j = 0; j < 4; ++j) { f[j] = (short)lo[j]; f[4 + j] = (short)hi[j]; }
    return f;
}

// ---------------------------------------------------------------------------
// Fused QKV projection, bf16 MFMA. C[8192 x 192] = X[8192 x 2048] * W^T.
// One block = 64 rows x all 192 cols, 512 threads = 8 waves tiled 2(M) x 4(N):
// wave owns 32 rows x 48 cols = 2x3 fragments. BK=64, single-buffer LDS,
// stride-72 rows (even bank distribution for b128 writes and b64 frag reads).
// Epilogue adds bias and folds softmax scale (0.125*log2e) into q.
// ---------------------------------------------------------------------------
__global__ __launch_bounds__(512) void proj_mfma_kernel(
    const float* __restrict__ x,
    const float* __restrict__ Wq, const float* __restrict__ bq,
    const float* __restrict__ Wk, const float* __restrict__ bk,
    const float* __restrict__ Wv, const float* __restrict__ bv,
    __hip_bfloat16* __restrict__ qb, __hip_bfloat16* __restrict__ kb,
    __hip_bfloat16* __restrict__ vb)
{
    __shared__ unsigned short xs[64 * 72];
    __shared__ unsigned short wl[192 * 72];

    const int tid  = threadIdx.x;
    const int w    = tid >> 6;
    const int l    = tid & 63;
    const int r    = l & 15;
    const int g    = l >> 4;
    const int wm   = w >> 2;   // 0..1 : M half
    const int wn   = w & 3;    // 0..3 : 48-col slice
    const int row0 = blockIdx.x * 64;

    const int srow = tid >> 3;        // 0..63 staging row
    const int scol = (tid & 7) * 8;   // 0..56 staging col (8 floats)

    const float* xrow = x + (size_t)(row0 + srow) * E_DIM + scol;
    const float* wrow0 = Wq + (size_t)srow * E_DIM + scol;
    const float* wrow1 = Wk + (size_t)srow * E_DIM + scol;
    const float* wrow2 = Wv + (size_t)srow * E_DIM + scol;

    f32x4 acc[2][3];
    #pragma unroll
    for (int mi = 0; mi < 2; ++mi)
        #pragma unroll
        for (int nt = 0; nt < 3; ++nt) acc[mi][nt] = (f32x4){0.f, 0.f, 0.f, 0.f};

    for (int k0 = 0; k0 < E_DIM; k0 += 64) {
        // issue global loads early (overlap with previous iteration's MFMAs)
        float4 xv0 = *(const float4*)(xrow + k0);
        float4 xv1 = *(const float4*)(xrow + k0 + 4);
        float4 wv00 = *(const float4*)(wrow0 + k0);
        float4 wv01 = *(const float4*)(wrow0 + k0 + 4);
        float4 wv10 = *(const float4*)(wrow1 + k0);
        float4 wv11 = *(const float4*)(wrow1 + k0 + 4);
        float4 wv20 = *(const float4*)(wrow2 + k0);
        float4 wv21 = *(const float4*)(wrow2 + k0 + 4);

        __syncthreads();  // previous iteration's fragment reads done
        *(u16x8*)&xs[srow * 72 + scol]         = cvt8(xv0, xv1);
        *(u16x8*)&wl[srow * 72 + scol]         = cvt8(wv00, wv01);
        *(u16x8*)&wl[(64 + srow) * 72 + scol]  = cvt8(wv10, wv11);
        *(u16x8*)&wl[(128 + srow) * 72 + scol] = cvt8(wv20, wv21);
        __syncthreads();

        bf16x8 af[2][2], bfm[2][3];
        #pragma unroll
        for (int kk = 0; kk < 2; ++kk) {
            #pragma unroll
            for (int mi = 0; mi < 2; ++mi)
                af[kk][mi] = ldfrag(&xs[(wm * 32 + mi * 16 + r) * 72 + kk * 32 + 4 * g]);
            #pragma unroll
            for (int nt = 0; nt < 3; ++nt)
                bfm[kk][nt] = ldfrag(&wl[(wn * 48 + nt * 16 + r) * 72 + kk * 32 + 4 * g]);
        }
        #pragma unroll
        for (int kk = 0; kk < 2; ++kk)
            #pragma unroll
            for (int mi = 0; mi < 2; ++mi)
                #pragma unroll
                for (int nt = 0; nt < 3; ++nt)
                    acc[mi][nt] = __builtin_amdgcn_mfma_f32_16x16x32_bf16(
                        af[kk][mi], bfm[kk][nt], acc[mi][nt], 0, 0, 0);
    }

    // epilogue: bias + scale, write bf16 to q/k/v
    #pragma unroll
    for (int nt = 0; nt < 3; ++nt) {
        const int b0 = wn * 48 + nt * 16;     // global col base, multiple of 16
        const int pj = b0 >> 6;               // which projection
        const int o  = (b0 & 63) + r;         // output dim within projection
        const float* bias = (pj == 0) ? bq : (pj == 1) ? bk : bv;
        __hip_bfloat16* dst = (pj == 0) ? qb : (pj == 1) ? kb : vb;
        const float scale = (pj == 0) ? 0.18033688011112042f : 1.0f;  // 0.125*log2e
        const float bv_ = bias[o];
        #pragma unroll
        for (int mi = 0; mi < 2; ++mi) {
            #pragma unroll
            for (int j = 0; j < 4; ++j) {
                const int row = row0 + wm * 32 + mi * 16 + 4 * g + j;
                dst[(size_t)row * D_HEAD + o] =
                    __float2bfloat16((acc[mi][nt][j] + bv_) * scale);
            }
        }
    }
}

// ---------------------------------------------------------------------------
// Flash attention, bf16 MFMA 16x16x32 (unchanged from round 1).
// ---------------------------------------------------------------------------
#define LDK 72
#define LDV 36
#define LDP 36

__global__ __launch_bounds__(128) void attn_mfma_kernel(
    const __hip_bfloat16* __restrict__ qg, const __hip_bfloat16* __restrict__ kg,
    const __hip_bfloat16* __restrict__ vg, float* __restrict__ out)
{
    __shared__ unsigned short Kl[32 * LDK];
    __shared__ unsigned short Vt[64 * LDV];
    __shared__ unsigned short Pl[2 * 16 * LDP];

    const int tid = threadIdx.x;
    const int w   = tid >> 6;
    const int l   = tid & 63;
    const int r   = l & 15;
    const int g   = l >> 4;
    const int q0  = blockIdx.x * 32;
    const int b   = blockIdx.y;
    const size_t base = (size_t)b * T_SEQ;

    const unsigned short* qb16 = (const unsigned short*)qg;
    const unsigned short* kb16 = (const unsigned short*)kg;
    const unsigned short* vb16 = (const unsigned short*)vg;

    const unsigned short* qrow = qb16 + (base + q0 + 16 * w + r) * D_HEAD;
    bf16x8 qf[2];
    #pragma unroll
    for (int kk = 0; kk < 2; ++kk) {
        u16x4 lo = *(const u16x4*)(qrow + 32 * kk + 4 * g);
        u16x4 hi = *(const u16x4*)(qrow + 32 * kk + 16 + 4 * g);
        #pragma unroll
        for (int j = 0; j < 4; ++j) {
            qf[kk][j]     = (short)lo[j];
            qf[kk][4 + j] = (short)hi[j];
        }
    }

    f32x4 acc_o[4];
    #pragma unroll
    for (int dn = 0; dn < 4; ++dn) acc_o[dn] = (f32x4){0.f, 0.f, 0.f, 0.f};
    float m4[4] = {-1e30f, -1e30f, -1e30f, -1e30f};
    float l4[4] = {0.f, 0.f, 0.f, 0.f};

    unsigned short* pw = &Pl[w * 16 * LDP];
    const int ntiles = q0 / 32 + 1;

    for (int it = 0; it < ntiles; ++it) {
        const int s0 = it * 32;

        __syncthreads();
        for (int c = tid; c < 256; c += 128) {
            const int row = c >> 3;
            const int dc  = (c & 7) * 8;
            const size_t gb = (base + s0 + row) * D_HEAD + dc;
            u16x8 k8 = *(const u16x8*)(kb16 + gb);
            *(u16x8*)(&Kl[row * LDK + dc]) = k8;
            u16x8 v8 = *(const u16x8*)(vb16 + gb);
            #pragma unroll
            for (int i = 0; i < 8; ++i) Vt[(dc + i) * LDV + row] = v8[i];
        }
        __syncthreads();

        f32x4 s_acc[2];
        s_acc[0] = (f32x4){0.f, 0.f, 0.f, 0.f};
        s_acc[1] = (f32x4){0.f, 0.f, 0.f, 0.f};
        #pragma unroll
        for (int nt = 0; nt < 2; ++nt) {
            #pragma unroll
            for (int kk = 0; kk < 2; ++kk) {
                const unsigned short* kp = &Kl[(nt * 16 + r) * LDK + kk * 32 + 4 * g];
                u16x4 blo = *(const u16x4*)kp;
                u16x4 bhi = *(const u16x4*)(kp + 16);
                bf16x8 bf;
                #pragma unroll
                for (int j = 0; j < 4; ++j) {
                    bf[j]     = (short)blo[j];
                    bf[4 + j] = (short)bhi[j];
                }
                s_acc[nt] = __builtin_amdgcn_mfma_f32_16x16x32_bf16(qf[kk], bf, s_acc[nt], 0, 0, 0);
            }
        }

        if (s0 == q0) {
            #pragma unroll
            for (int nt = 0; nt < 2; ++nt)
                #pragma unroll
                for (int j = 0; j < 4; ++j)
                    if (nt * 16 + r > 16 * w + 4 * g + j) s_acc[nt][j] = -1e30f;
        }

        float tm[4];
        #pragma unroll
        for (int j = 0; j < 4; ++j) tm[j] = fmaxf(s_acc[0][j], s_acc[1][j]);
        #pragma unroll
        for (int mask = 1; mask < 16; mask <<= 1)
            #pragma unroll
            for (int j = 0; j < 4; ++j)
                tm[j] = fmaxf(tm[j], __shfl_xor(tm[j], mask));

        float p0[4], p1[4], rs[4];
        #pragma unroll
        for (int j = 0; j < 4; ++j) {
            const float mn = fmaxf(m4[j], tm[j]);
            const float sc = exp2f(m4[j] - mn);
            m4[j] = mn;
            p0[j] = exp2f(s_acc[0][j] - mn);
            p1[j] = exp2f(s_acc[1][j] - mn);
            rs[j] = p0[j] + p1[j];
            l4[j] *= sc;
            acc_o[0][j] *= sc; acc_o[1][j] *= sc;
            acc_o[2][j] *= sc; acc_o[3][j] *= sc;
        }
        #pragma unroll
        for (int mask = 1; mask < 16; mask <<= 1)
            #pragma unroll
            for (int j = 0; j < 4; ++j)
                rs[j] += __shfl_xor(rs[j], mask);
        #pragma unroll
        for (int j = 0; j < 4; ++j) l4[j] += rs[j];

        #pragma unroll
        for (int j = 0; j < 4; ++j) {
            pw[(4 * g + j) * LDP + r]      = f2bf(p0[j]);
            pw[(4 * g + j) * LDP + 16 + r] = f2bf(p1[j]);
        }

        u16x4 plo = *(const u16x4*)&pw[r * LDP + 4 * g];
        u16x4 phi = *(const u16x4*)&pw[r * LDP + 16 + 4 * g];
        bf16x8 pf;
        #pragma unroll
        for (int j = 0; j < 4; ++j) {
            pf[j]     = (short)plo[j];
            pf[4 + j] = (short)phi[j];
        }
        #pragma unroll
        for (int dn = 0; dn < 4; ++dn) {
            const unsigned short* vp = &Vt[(dn * 16 + r) * LDV + 4 * g];
            u16x4 vlo = *(const u16x4*)vp;
            u16x4 vhi = *(const u16x4*)(vp + 16);
            bf16x8 vf;
            #pragma unroll
            for (int j = 0; j < 4; ++j) {
                vf[j]     = (short)vlo[j];
                vf[4 + j] = (short)vhi[j];
            }
            acc_o[dn] = __builtin_amdgcn_mfma_f32_16x16x32_bf16(pf, vf, acc_o[dn], 0, 0, 0);
        }
    }

    #pragma unroll
    for (int j = 0; j < 4; ++j) {
        const float inv = 1.0f / l4[j];
        const int row = q0 + 16 * w + 4 * g + j;
        float* op = out + (base + row) * D_HEAD;
        #pragma unroll
        for (int dn = 0; dn < 4; ++dn)
            op[dn * 16 + r] = acc_o[dn][j] * inv;
    }
}

extern "C" void kernel_launch(void* const* d_in, const int* in_sizes, int n_in,
                              void* d_out, int out_size, void* d_ws, size_t ws_size,
                              hipStream_t stream) {
    const float* x  = (const float*)d_in[0];
    const float* Wq = (const float*)d_in[1];
    const float* bq = (const float*)d_in[2];
    const float* Wk = (const float*)d_in[3];
    const float* bk = (const float*)d_in[4];
    const float* Wv = (const float*)d_in[5];
    const float* bv = (const float*)d_in[6];
    float* out = (float*)d_out;

    __hip_bfloat16* qb = (__hip_bfloat16*)d_ws;
    __hip_bfloat16* kb = qb + (size_t)NROWS * D_HEAD;
    __hip_bfloat16* vb = kb + (size_t)NROWS * D_HEAD;

    proj_mfma_kernel<<<NROWS / 64, 512, 0, stream>>>(x, Wq, bq, Wk, bk, Wv, bv, qb, kb, vb);
    dim3 agrid(T_SEQ / 32, B_SZ);
    attn_mfma_kernel<<<agrid, 128, 0, stream>>>(qb, kb, vb, out);
}

// Round 4
// 148.518 us; speedup vs baseline: 3.8063x; 1.3371x over previous
//
#include <hip/hip_runtime.h>
#include <hip/hip_bf16.h>

#define T_SEQ 2048
#define E_DIM 2048
#define D_HEAD 64
#define B_SZ 4
#define NROWS (B_SZ * T_SEQ)  // 8192

typedef __attribute__((ext_vector_type(8))) short bf16x8;
typedef __attribute__((ext_vector_type(4))) float f32x4;
typedef __attribute__((ext_vector_type(4))) unsigned short u16x4;
typedef __attribute__((ext_vector_type(8))) unsigned short u16x8;

__device__ __forceinline__ unsigned short f2bf(float x) {
    __hip_bfloat16 h = __float2bfloat16(x);
    return *reinterpret_cast<unsigned short*>(&h);
}

__device__ __forceinline__ u16x8 cvt8(float4 a, float4 b) {
    u16x8 t;
    t[0] = f2bf(a.x); t[1] = f2bf(a.y); t[2] = f2bf(a.z); t[3] = f2bf(a.w);
    t[4] = f2bf(b.x); t[5] = f2bf(b.y); t[6] = f2bf(b.z); t[7] = f2bf(b.w);
    return t;
}

// MFMA A/B fragment from a [row][k] bf16 buffer (LDS or global): k = base..base+3, base+16..+19
__device__ __forceinline__ bf16x8 ldfrag(const unsigned short* p) {
    u16x4 lo = *(const u16x4*)p;
    u16x4 hi = *(const u16x4*)(p + 16);
    bf16x8 f;
    #pragma unroll
    for (int j = 0; j < 4; ++j) { f[j] = (short)lo[j]; f[4 + j] = (short)hi[j]; }
    return f;
}

// ---------------------------------------------------------------------------
// W -> bf16, layout [3][64][2048] (row-major per projection)
// ---------------------------------------------------------------------------
__global__ __launch_bounds__(256) void wcvt_kernel(
    const float* __restrict__ Wq, const float* __restrict__ Wk,
    const float* __restrict__ Wv, unsigned short* __restrict__ dst)
{
    const int m = blockIdx.y;
    const float* __restrict__ src = (m == 0) ? Wq : (m == 1) ? Wk : Wv;
    const int i = (blockIdx.x * 256 + threadIdx.x) * 8;  // 0..131064
    float4 a = *(const float4*)(src + i);
    float4 b = *(const float4*)(src + i + 4);
    *(u16x8*)(dst + (size_t)m * 131072 + i) = cvt8(a, b);
}

// ---------------------------------------------------------------------------
// Fused QKV projection. C[8192 x 192] = X * W^T. BM=32 rows/block -> 256
// blocks x 512 threads (8 waves, 2M x 4N; wave = 16 rows x 48 cols).
// x staged through LDS (fp32->bf16); W fragments loaded DIRECTLY from
// L2-resident bf16 global (no W LDS, no W cvt in loop). BK=64.
// Epilogue adds bias; q gets 0.125*log2e folded in.
// ---------------------------------------------------------------------------
__global__ __launch_bounds__(512) void proj_mfma_kernel(
    const float* __restrict__ x, const unsigned short* __restrict__ Wb,
    const float* __restrict__ bq, const float* __restrict__ bk,
    const float* __restrict__ bv,
    __hip_bfloat16* __restrict__ qb, __hip_bfloat16* __restrict__ kb,
    __hip_bfloat16* __restrict__ vb)
{
    __shared__ unsigned short xs[32 * 72];

    const int tid  = threadIdx.x;
    const int w    = tid >> 6;
    const int l    = tid & 63;
    const int r    = l & 15;
    const int g    = l >> 4;
    const int wm   = w >> 2;   // 0..1 : 16-row half
    const int wn   = w & 3;    // 0..3 : 48-col slice
    const int row0 = blockIdx.x * 32;

    // W fragment row pointers (global bf16, [192][2048])
    const unsigned short* wp[3];
    #pragma unroll
    for (int nt = 0; nt < 3; ++nt)
        wp[nt] = Wb + (size_t)(wn * 48 + nt * 16 + r) * E_DIM + 4 * g;

    const int srow = tid >> 3;        // 0..63 (only <32 used for x)
    const int scol = (tid & 7) * 8;
    const float* xrow = x + (size_t)(row0 + srow) * E_DIM + scol;

    f32x4 acc[3];
    #pragma unroll
    for (int nt = 0; nt < 3; ++nt) acc[nt] = (f32x4){0.f, 0.f, 0.f, 0.f};

    for (int k0 = 0; k0 < E_DIM; k0 += 64) {
        // B fragments from global (L2) — issue early, latency hides under staging
        bf16x8 bfm[2][3];
        #pragma unroll
        for (int kk = 0; kk < 2; ++kk)
            #pragma unroll
            for (int nt = 0; nt < 3; ++nt)
                bfm[kk][nt] = ldfrag(wp[nt] + k0 + kk * 32);

        float4 xv0, xv1;
        if (tid < 256) {
            xv0 = *(const float4*)(xrow + k0);
            xv1 = *(const float4*)(xrow + k0 + 4);
        }
        __syncthreads();  // prior iteration's A-frag reads done
        if (tid < 256) *(u16x8*)&xs[srow * 72 + scol] = cvt8(xv0, xv1);
        __syncthreads();

        bf16x8 af[2];
        #pragma unroll
        for (int kk = 0; kk < 2; ++kk)
            af[kk] = ldfrag(&xs[(wm * 16 + r) * 72 + kk * 32 + 4 * g]);

        #pragma unroll
        for (int kk = 0; kk < 2; ++kk)
            #pragma unroll
            for (int nt = 0; nt < 3; ++nt)
                acc[nt] = __builtin_amdgcn_mfma_f32_16x16x32_bf16(
                    af[kk], bfm[kk][nt], acc[nt], 0, 0, 0);
    }

    #pragma unroll
    for (int nt = 0; nt < 3; ++nt) {
        const int b0 = wn * 48 + nt * 16;
        const int pj = b0 >> 6;
        const int o  = (b0 & 63) + r;
        const float* bias = (pj == 0) ? bq : (pj == 1) ? bk : bv;
        __hip_bfloat16* dst = (pj == 0) ? qb : (pj == 1) ? kb : vb;
        const float scale = (pj == 0) ? 0.18033688011112042f : 1.0f;  // 0.125*log2e
        const float bv_ = bias[o];
        #pragma unroll
        for (int j = 0; j < 4; ++j) {
            const int row = row0 + wm * 16 + 4 * g + j;
            dst[(size_t)row * D_HEAD + o] =
                __float2bfloat16((acc[nt][j] + bv_) * scale);
        }
    }
}

// ---------------------------------------------------------------------------
// Split-KV flash attention partials. Block = 128 thr = 2 waves, 32 q-rows.
// Grid (qt, ch, b). Chunk = tpc s-tiles of 32. Writes UNNORMALIZED partial
// O (32x64 f32) + per-row (m, l) in log2 domain.
// ---------------------------------------------------------------------------
#define LDK 72
#define LDV 36
#define LDP 36

__global__ __launch_bounds__(128) void attn_part_kernel(
    const __hip_bfloat16* __restrict__ qg, const __hip_bfloat16* __restrict__ kg,
    const __hip_bfloat16* __restrict__ vg, float* __restrict__ Op,
    float* __restrict__ Ml, int tpc, int nch)
{
    const int qt = blockIdx.x;
    const int ch = blockIdx.y;
    if (ch * tpc > qt) return;  // entirely above diagonal

    __shared__ unsigned short Kl[32 * LDK];
    __shared__ unsigned short Vt[64 * LDV];
    __shared__ unsigned short Pl[2 * 16 * LDP];

    const int tid = threadIdx.x;
    const int w   = tid >> 6;
    const int l   = tid & 63;
    const int r   = l & 15;
    const int g   = l >> 4;
    const int q0  = qt * 32;
    const int b   = blockIdx.z;
    const size_t base = (size_t)b * T_SEQ;

    const unsigned short* qb16 = (const unsigned short*)qg;
    const unsigned short* kb16 = (const unsigned short*)kg;
    const unsigned short* vb16 = (const unsigned short*)vg;

    const unsigned short* qrow = qb16 + (base + q0 + 16 * w + r) * D_HEAD;
    bf16x8 qf[2];
    #pragma unroll
    for (int kk = 0; kk < 2; ++kk) {
        u16x4 lo = *(const u16x4*)(qrow + 32 * kk + 4 * g);
        u16x4 hi = *(const u16x4*)(qrow + 32 * kk + 16 + 4 * g);
        #pragma unroll
        for (int j = 0; j < 4; ++j) {
            qf[kk][j]     = (short)lo[j];
            qf[kk][4 + j] = (short)hi[j];
        }
    }

    f32x4 acc_o[4];
    #pragma unroll
    for (int dn = 0; dn < 4; ++dn) acc_o[dn] = (f32x4){0.f, 0.f, 0.f, 0.f};
    float m4[4] = {-1e30f, -1e30f, -1e30f, -1e30f};
    float l4[4] = {0.f, 0.f, 0.f, 0.f};

    unsigned short* pw = &Pl[w * 16 * LDP];
    const int ntiles = min(tpc, qt + 1 - tpc * ch);

    for (int it = 0; it < ntiles; ++it) {
        const int s0 = (ch * tpc + it) * 32;

        __syncthreads();
        for (int c = tid; c < 256; c += 128) {
            const int row = c >> 3;
            const int dc  = (c & 7) * 8;
            const size_t gb = (base + s0 + row) * D_HEAD + dc;
            u16x8 k8 = *(const u16x8*)(kb16 + gb);
            *(u16x8*)(&Kl[row * LDK + dc]) = k8;
            u16x8 v8 = *(const u16x8*)(vb16 + gb);
            #pragma unroll
            for (int i = 0; i < 8; ++i) Vt[(dc + i) * LDV + row] = v8[i];
        }
        __syncthreads();

        f32x4 s_acc[2];
        s_acc[0] = (f32x4){0.f, 0.f, 0.f, 0.f};
        s_acc[1] = (f32x4){0.f, 0.f, 0.f, 0.f};
        #pragma unroll
        for (int nt = 0; nt < 2; ++nt) {
            #pragma unroll
            for (int kk = 0; kk < 2; ++kk) {
                const unsigned short* kp = &Kl[(nt * 16 + r) * LDK + kk * 32 + 4 * g];
                bf16x8 bf = ldfrag(kp);
                s_acc[nt] = __builtin_amdgcn_mfma_f32_16x16x32_bf16(qf[kk], bf, s_acc[nt], 0, 0, 0);
            }
        }

        if (s0 == q0) {  // diagonal tile: causal mask
            #pragma unroll
            for (int nt = 0; nt < 2; ++nt)
                #pragma unroll
                for (int j = 0; j < 4; ++j)
                    if (nt * 16 + r > 16 * w + 4 * g + j) s_acc[nt][j] = -1e30f;
        }

        float tm[4];
        #pragma unroll
        for (int j = 0; j < 4; ++j) tm[j] = fmaxf(s_acc[0][j], s_acc[1][j]);
        #pragma unroll
        for (int mask = 1; mask < 16; mask <<= 1)
            #pragma unroll
            for (int j = 0; j < 4; ++j)
                tm[j] = fmaxf(tm[j], __shfl_xor(tm[j], mask));

        float p0[4], p1[4], rs[4];
        #pragma unroll
        for (int j = 0; j < 4; ++j) {
            const float mn = fmaxf(m4[j], tm[j]);
            const float sc = exp2f(m4[j] - mn);
            m4[j] = mn;
            p0[j] = exp2f(s_acc[0][j] - mn);
            p1[j] = exp2f(s_acc[1][j] - mn);
            rs[j] = p0[j] + p1[j];
            l4[j] *= sc;
            acc_o[0][j] *= sc; acc_o[1][j] *= sc;
            acc_o[2][j] *= sc; acc_o[3][j] *= sc;
        }
        #pragma unroll
        for (int mask = 1; mask < 16; mask <<= 1)
            #pragma unroll
            for (int j = 0; j < 4; ++j)
                rs[j] += __shfl_xor(rs[j], mask);
        #pragma unroll
        for (int j = 0; j < 4; ++j) l4[j] += rs[j];

        #pragma unroll
        for (int j = 0; j < 4; ++j) {
            pw[(4 * g + j) * LDP + r]      = f2bf(p0[j]);
            pw[(4 * g + j) * LDP + 16 + r] = f2bf(p1[j]);
        }

        bf16x8 pf;
        {
            u16x4 plo = *(const u16x4*)&pw[r * LDP + 4 * g];
            u16x4 phi = *(const u16x4*)&pw[r * LDP + 16 + 4 * g];
            #pragma unroll
            for (int j = 0; j < 4; ++j) { pf[j] = (short)plo[j]; pf[4 + j] = (short)phi[j]; }
        }
        #pragma unroll
        for (int dn = 0; dn < 4; ++dn) {
            const unsigned short* vp = &Vt[(dn * 16 + r) * LDV + 4 * g];
            bf16x8 vf = ldfrag(vp);
            acc_o[dn] = __builtin_amdgcn_mfma_f32_16x16x32_bf16(pf, vf, acc_o[dn], 0, 0, 0);
        }
    }

    // write unnormalized partials
    const size_t pidx = ((size_t)(b * 64 + qt) * nch + ch);
    float* op = Op + pidx * 2048;
    #pragma unroll
    for (int j = 0; j < 4; ++j) {
        const int row = 16 * w + 4 * g + j;
        #pragma unroll
        for (int dn = 0; dn < 4; ++dn)
            op[row * 64 + dn * 16 + r] = acc_o[dn][j];
        if (r == 0) {
            Ml[pidx * 64 + row]      = m4[j];
            Ml[pidx * 64 + 32 + row] = l4[j];
        }
    }
}

// ---------------------------------------------------------------------------
// Combine partials: out[row][d] = sum_c 2^(m_c-M) O_c / sum_c 2^(m_c-M) l_c
// Block per (qt, b), 256 threads.
// ---------------------------------------------------------------------------
__global__ __launch_bounds__(256) void attn_combine_kernel(
    const float* __restrict__ Op, const float* __restrict__ Ml,
    float* __restrict__ out, int tpc, int nch)
{
    const int qt = blockIdx.x;
    const int b  = blockIdx.y;
    const int nact = qt / tpc + 1;
    const size_t pbase = (size_t)(b * 64 + qt) * nch;

    __shared__ float wgt[8][32];
    __shared__ float linv[32];

    const int tid = threadIdx.x;
    if (tid < 32) {
        float M = -1e30f;
        for (int c = 0; c < nact; ++c)
            M = fmaxf(M, Ml[(pbase + c) * 64 + tid]);
        float L = 0.f;
        for (int c = 0; c < nact; ++c) {
            float wv = exp2f(Ml[(pbase + c) * 64 + tid] - M);
            wgt[c][tid] = wv;
            L += wv * Ml[(pbase + c) * 64 + 32 + tid];
        }
        linv[tid] = 1.0f / L;
    }
    __syncthreads();

    const int d  = tid & 63;
    const int r0 = tid >> 6;
    for (int row = r0; row < 32; row += 4) {
        float a = 0.f;
        for (int c = 0; c < nact; ++c)
            a += wgt[c][row] * Op[(pbase + c) * 2048 + row * 64 + d];
        out[((size_t)b * T_SEQ + qt * 32 + row) * D_HEAD + d] = a * linv[row];
    }
}

extern "C" void kernel_launch(void* const* d_in, const int* in_sizes, int n_in,
                              void* d_out, int out_size, void* d_ws, size_t ws_size,
                              hipStream_t stream) {
    const float* x  = (const float*)d_in[0];
    const float* Wq = (const float*)d_in[1];
    const float* bq = (const float*)d_in[2];
    const float* Wk = (const float*)d_in[3];
    const float* bk = (const float*)d_in[4];
    const float* Wv = (const float*)d_in[5];
    const float* bv = (const float*)d_in[6];
    float* out = (float*)d_out;

    // workspace layout
    __hip_bfloat16* qb = (__hip_bfloat16*)d_ws;
    __hip_bfloat16* kb = qb + (size_t)NROWS * D_HEAD;
    __hip_bfloat16* vb = kb + (size_t)NROWS * D_HEAD;
    unsigned short* Wb = (unsigned short*)(vb + (size_t)NROWS * D_HEAD);  // 3*64*2048
    float* Op = (float*)((char*)d_ws + (4u << 20));

    // pick chunk count by available workspace (deterministic: ws_size is fixed)
    int nch = 8;
    while (nch > 1 &&
           (4u << 20) + (size_t)256 * nch * (2048 + 64) * 4 > ws_size)
        nch >>= 1;
    const int tpc = 64 / nch;  // s-tiles (of 32) per chunk
    float* Ml = Op + (size_t)256 * nch * 2048;

    wcvt_kernel<<<dim3(64, 3), 256, 0, stream>>>(Wq, Wk, Wv, Wb);
    proj_mfma_kernel<<<NROWS / 32, 512, 0, stream>>>(x, Wb, bq, bk, bv, qb, kb, vb);
    attn_part_kernel<<<dim3(64, nch, B_SZ), 128, 0, stream>>>(qb, kb, vb, Op, Ml, tpc, nch);
    attn_combine_kernel<<<dim3(64, B_SZ), 256, 0, stream>>>(Op, Ml, out, tpc, nch);
}

// Round 5
// 84.591 us; speedup vs baseline: 6.6828x; 1.7557x over previous
//
#include <hip/hip_runtime.h>
#include <hip/hip_bf16.h>

#define T_SEQ 2048
#define E_DIM 2048
#define D_HEAD 64
#define B_SZ 4
#define NROWS (B_SZ * T_SEQ)  // 8192

typedef __attribute__((ext_vector_type(8))) short bf16x8;
typedef __attribute__((ext_vector_type(4))) float f32x4;
typedef __attribute__((ext_vector_type(4))) unsigned short u16x4;
typedef __attribute__((ext_vector_type(8))) unsigned short u16x8;

__device__ __forceinline__ unsigned short f2bf(float x) {
    __hip_bfloat16 h = __float2bfloat16(x);
    return *reinterpret_cast<unsigned short*>(&h);
}

__device__ __forceinline__ u16x8 cvt8(float4 a, float4 b) {
    u16x8 t;
    t[0] = f2bf(a.x); t[1] = f2bf(a.y); t[2] = f2bf(a.z); t[3] = f2bf(a.w);
    t[4] = f2bf(b.x); t[5] = f2bf(b.y); t[6] = f2bf(b.z); t[7] = f2bf(b.w);
    return t;
}

__device__ __forceinline__ u16x4 cvt4(float4 a) {
    u16x4 t;
    t[0] = f2bf(a.x); t[1] = f2bf(a.y); t[2] = f2bf(a.z); t[3] = f2bf(a.w);
    return t;
}

// MFMA A/B fragment from a [row][k] bf16 buffer: k = base..base+3, base+16..+19
__device__ __forceinline__ bf16x8 ldfrag(const unsigned short* p) {
    u16x4 lo = *(const u16x4*)p;
    u16x4 hi = *(const u16x4*)(p + 16);
    bf16x8 f;
    #pragma unroll
    for (int j = 0; j < 4; ++j) { f[j] = (short)lo[j]; f[4 + j] = (short)hi[j]; }
    return f;
}

// ---------------------------------------------------------------------------
// W -> bf16 packed in MFMA B-fragment order:
// Wp[((wn*3+nt)*64 + k32)*512 + l*8 + e]; lane l=(g<<4)|r holds, for frag row
// n = wn*48+nt*16+r, elems k = k32*32 + {g*4..g*4+3, 16+g*4..16+g*4+3}.
// One coalesced u16x8 per lane at GEMM time.
// ---------------------------------------------------------------------------
__global__ __launch_bounds__(256) void wcvt_kernel(
    const float* __restrict__ Wq, const float* __restrict__ Wk,
    const float* __restrict__ Wv, unsigned short* __restrict__ Wp)
{
    const int gid = blockIdx.x * 256 + threadIdx.x;   // 0..49151
    const int l    = gid & 63;
    const int k32  = (gid >> 6) & 63;
    const int rest = gid >> 12;                       // 0..11
    const int nt   = rest % 3;
    const int wn   = rest / 3;
    const int r    = l & 15;
    const int g    = l >> 4;
    const int n    = wn * 48 + nt * 16 + r;           // 0..191
    const int pj   = n >> 6;
    const int o    = n & 63;
    const float* __restrict__ src = (pj == 0) ? Wq : (pj == 1) ? Wk : Wv;
    const float* p = src + (size_t)o * E_DIM + k32 * 32 + g * 4;
    float4 a = *(const float4*)p;
    float4 b = *(const float4*)(p + 16);
    *(u16x8*)(Wp + (size_t)gid * 8) = cvt8(a, b);
}

// ---------------------------------------------------------------------------
// Fused QKV projection. C[8192 x 192] = X * W^T. BM=32, 512 thr = 8 waves
// (2M x 4N; wave = 16 rows x 48 cols). Double-buffered x LDS, ONE barrier
// per K-step, x prefetched 2 steps ahead (regs), W-frags 1 step ahead from
// packed L2-resident Wp (coalesced 16B/lane). Epilogue: bias (+0.125*log2e
// scale folded into q) -> bf16.
// ---------------------------------------------------------------------------
__global__ __launch_bounds__(512) void proj_mfma_kernel(
    const float* __restrict__ x, const unsigned short* __restrict__ Wp,
    const float* __restrict__ bq, const float* __restrict__ bk,
    const float* __restrict__ bv,
    __hip_bfloat16* __restrict__ qb, __hip_bfloat16* __restrict__ kb,
    __hip_bfloat16* __restrict__ vb)
{
    __shared__ unsigned short xs[2][32 * 72];

    const int tid  = threadIdx.x;
    const int w    = tid >> 6;
    const int l    = tid & 63;
    const int r    = l & 15;
    const int g    = l >> 4;
    const int wm   = w >> 2;   // 0..1 : 16-row half
    const int wn   = w & 3;    // 0..3 : 48-col slice
    const int row0 = blockIdx.x * 32;

    const int srow = tid >> 4;         // 0..31
    const int sc4  = (tid & 15) * 4;   // 0..60
    const float* xptr = x + (size_t)(row0 + srow) * E_DIM + sc4;

    // packed W base for this wave's wn slice; frag (nt,k32) at +((nt*64+k32)*512 + l*8)
    const unsigned short* wbase = Wp + (size_t)wn * 3 * 64 * 512 + l * 8;

    f32x4 acc[3];
    #pragma unroll
    for (int nt = 0; nt < 3; ++nt) acc[nt] = (f32x4){0.f, 0.f, 0.f, 0.f};

    // prologue: x[0], B[0], x[1]; stage buf0
    float4 xv_a = *(const float4*)(xptr);           // k-step 0
    bf16x8 bcur[2][3];
    #pragma unroll
    for (int kk = 0; kk < 2; ++kk)
        #pragma unroll
        for (int nt = 0; nt < 3; ++nt)
            bcur[kk][nt] = *(const bf16x8*)(wbase + (size_t)(nt * 64 + kk) * 512);
    float4 xv_b = *(const float4*)(xptr + 64);      // k-step 1
    *(u16x4*)&xs[0][srow * 72 + sc4] = cvt4(xv_a);
    __syncthreads();

    for (int t = 0; t < 32; ++t) {
        const int cur = t & 1;

        // A fragments from LDS (current buffer)
        bf16x8 af[2];
        #pragma unroll
        for (int kk = 0; kk < 2; ++kk)
            af[kk] = ldfrag(&xs[cur][(wm * 16 + r) * 72 + kk * 32 + 4 * g]);

        // prefetch B[t+1] (L2) and x[t+2] (HBM)
        bf16x8 bnext[2][3];
        if (t < 31) {
            #pragma unroll
            for (int kk = 0; kk < 2; ++kk)
                #pragma unroll
                for (int nt = 0; nt < 3; ++nt)
                    bnext[kk][nt] = *(const bf16x8*)(
                        wbase + (size_t)(nt * 64 + (t + 1) * 2 + kk) * 512);
        }
        float4 xvn;
        if (t < 30) xvn = *(const float4*)(xptr + (t + 2) * 64);

        #pragma unroll
        for (int kk = 0; kk < 2; ++kk)
            #pragma unroll
            for (int nt = 0; nt < 3; ++nt)
                acc[nt] = __builtin_amdgcn_mfma_f32_16x16x32_bf16(
                    af[kk], bcur[kk][nt], acc[nt], 0, 0, 0);

        // stage next buffer (x[t+1] held in xv_b)
        if (t < 31) *(u16x4*)&xs[cur ^ 1][srow * 72 + sc4] = cvt4(xv_b);
        __syncthreads();

        xv_b = xvn;
        #pragma unroll
        for (int kk = 0; kk < 2; ++kk)
            #pragma unroll
            for (int nt = 0; nt < 3; ++nt)
                bcur[kk][nt] = bnext[kk][nt];
    }

    #pragma unroll
    for (int nt = 0; nt < 3; ++nt) {
        const int b0 = wn * 48 + nt * 16;
        const int pj = b0 >> 6;
        const int o  = (b0 & 63) + r;
        const float* bias = (pj == 0) ? bq : (pj == 1) ? bk : bv;
        __hip_bfloat16* dst = (pj == 0) ? qb : (pj == 1) ? kb : vb;
        const float scale = (pj == 0) ? 0.18033688011112042f : 1.0f;  // 0.125*log2e
        const float bv_ = bias[o];
        #pragma unroll
        for (int j = 0; j < 4; ++j) {
            const int row = row0 + wm * 16 + 4 * g + j;
            dst[(size_t)row * D_HEAD + o] =
                __float2bfloat16((acc[nt][j] + bv_) * scale);
        }
    }
}

// ---------------------------------------------------------------------------
// Split-KV flash attention partials (unchanged from round 3).
// ---------------------------------------------------------------------------
#define LDK 72
#define LDV 36
#define LDP 36

__global__ __launch_bounds__(128) void attn_part_kernel(
    const __hip_bfloat16* __restrict__ qg, const __hip_bfloat16* __restrict__ kg,
    const __hip_bfloat16* __restrict__ vg, float* __restrict__ Op,
    float* __restrict__ Ml, int tpc, int nch)
{
    const int qt = blockIdx.x;
    const int ch = blockIdx.y;
    if (ch * tpc > qt) return;

    __shared__ unsigned short Kl[32 * LDK];
    __shared__ unsigned short Vt[64 * LDV];
    __shared__ unsigned short Pl[2 * 16 * LDP];

    const int tid = threadIdx.x;
    const int w   = tid >> 6;
    const int l   = tid & 63;
    const int r   = l & 15;
    const int g   = l >> 4;
    const int q0  = qt * 32;
    const int b   = blockIdx.z;
    const size_t base = (size_t)b * T_SEQ;

    const unsigned short* qb16 = (const unsigned short*)qg;
    const unsigned short* kb16 = (const unsigned short*)kg;
    const unsigned short* vb16 = (const unsigned short*)vg;

    const unsigned short* qrow = qb16 + (base + q0 + 16 * w + r) * D_HEAD;
    bf16x8 qf[2];
    #pragma unroll
    for (int kk = 0; kk < 2; ++kk) {
        u16x4 lo = *(const u16x4*)(qrow + 32 * kk + 4 * g);
        u16x4 hi = *(const u16x4*)(qrow + 32 * kk + 16 + 4 * g);
        #pragma unroll
        for (int j = 0; j < 4; ++j) {
            qf[kk][j]     = (short)lo[j];
            qf[kk][4 + j] = (short)hi[j];
        }
    }

    f32x4 acc_o[4];
    #pragma unroll
    for (int dn = 0; dn < 4; ++dn) acc_o[dn] = (f32x4){0.f, 0.f, 0.f, 0.f};
    float m4[4] = {-1e30f, -1e30f, -1e30f, -1e30f};
    float l4[4] = {0.f, 0.f, 0.f, 0.f};

    unsigned short* pw = &Pl[w * 16 * LDP];
    const int ntiles = min(tpc, qt + 1 - tpc * ch);

    for (int it = 0; it < ntiles; ++it) {
        const int s0 = (ch * tpc + it) * 32;

        __syncthreads();
        for (int c = tid; c < 256; c += 128) {
            const int row = c >> 3;
            const int dc  = (c & 7) * 8;
            const size_t gb = (base + s0 + row) * D_HEAD + dc;
            u16x8 k8 = *(const u16x8*)(kb16 + gb);
            *(u16x8*)(&Kl[row * LDK + dc]) = k8;
            u16x8 v8 = *(const u16x8*)(vb16 + gb);
            #pragma unroll
            for (int i = 0; i < 8; ++i) Vt[(dc + i) * LDV + row] = v8[i];
        }
        __syncthreads();

        f32x4 s_acc[2];
        s_acc[0] = (f32x4){0.f, 0.f, 0.f, 0.f};
        s_acc[1] = (f32x4){0.f, 0.f, 0.f, 0.f};
        #pragma unroll
        for (int nt = 0; nt < 2; ++nt) {
            #pragma unroll
            for (int kk = 0; kk < 2; ++kk) {
                const unsigned short* kp = &Kl[(nt * 16 + r) * LDK + kk * 32 + 4 * g];
                bf16x8 bf = ldfrag(kp);
                s_acc[nt] = __builtin_amdgcn_mfma_f32_16x16x32_bf16(qf[kk], bf, s_acc[nt], 0, 0, 0);
            }
        }

        if (s0 == q0) {
            #pragma unroll
            for (int nt = 0; nt < 2; ++nt)
                #pragma unroll
                for (int j = 0; j < 4; ++j)
                    if (nt * 16 + r > 16 * w + 4 * g + j) s_acc[nt][j] = -1e30f;
        }

        float tm[4];
        #pragma unroll
        for (int j = 0; j < 4; ++j) tm[j] = fmaxf(s_acc[0][j], s_acc[1][j]);
        #pragma unroll
        for (int mask = 1; mask < 16; mask <<= 1)
            #pragma unroll
            for (int j = 0; j < 4; ++j)
                tm[j] = fmaxf(tm[j], __shfl_xor(tm[j], mask));

        float p0[4], p1[4], rs[4];
        #pragma unroll
        for (int j = 0; j < 4; ++j) {
            const float mn = fmaxf(m4[j], tm[j]);
            const float sc = exp2f(m4[j] - mn);
            m4[j] = mn;
            p0[j] = exp2f(s_acc[0][j] - mn);
            p1[j] = exp2f(s_acc[1][j] - mn);
            rs[j] = p0[j] + p1[j];
            l4[j] *= sc;
            acc_o[0][j] *= sc; acc_o[1][j] *= sc;
            acc_o[2][j] *= sc; acc_o[3][j] *= sc;
        }
        #pragma unroll
        for (int mask = 1; mask < 16; mask <<= 1)
            #pragma unroll
            for (int j = 0; j < 4; ++j)
                rs[j] += __shfl_xor(rs[j], mask);
        #pragma unroll
        for (int j = 0; j < 4; ++j) l4[j] += rs[j];

        #pragma unroll
        for (int j = 0; j < 4; ++j) {
            pw[(4 * g + j) * LDP + r]      = f2bf(p0[j]);
            pw[(4 * g + j) * LDP + 16 + r] = f2bf(p1[j]);
        }

        bf16x8 pf;
        {
            u16x4 plo = *(const u16x4*)&pw[r * LDP + 4 * g];
            u16x4 phi = *(const u16x4*)&pw[r * LDP + 16 + 4 * g];
            #pragma unroll
            for (int j = 0; j < 4; ++j) { pf[j] = (short)plo[j]; pf[4 + j] = (short)phi[j]; }
        }
        #pragma unroll
        for (int dn = 0; dn < 4; ++dn) {
            const unsigned short* vp = &Vt[(dn * 16 + r) * LDV + 4 * g];
            bf16x8 vf = ldfrag(vp);
            acc_o[dn] = __builtin_amdgcn_mfma_f32_16x16x32_bf16(pf, vf, acc_o[dn], 0, 0, 0);
        }
    }

    const size_t pidx = ((size_t)(b * 64 + qt) * nch + ch);
    float* op = Op + pidx * 2048;
    #pragma unroll
    for (int j = 0; j < 4; ++j) {
        const int row = 16 * w + 4 * g + j;
        #pragma unroll
        for (int dn = 0; dn < 4; ++dn)
            op[row * 64 + dn * 16 + r] = acc_o[dn][j];
        if (r == 0) {
            Ml[pidx * 64 + row]      = m4[j];
            Ml[pidx * 64 + 32 + row] = l4[j];
        }
    }
}

// ---------------------------------------------------------------------------
// Combine partials (unchanged from round 3).
// ---------------------------------------------------------------------------
__global__ __launch_bounds__(256) void attn_combine_kernel(
    const float* __restrict__ Op, const float* __restrict__ Ml,
    float* __restrict__ out, int tpc, int nch)
{
    const int qt = blockIdx.x;
    const int b  = blockIdx.y;
    const int nact = qt / tpc + 1;
    const size_t pbase = (size_t)(b * 64 + qt) * nch;

    __shared__ float wgt[8][32];
    __shared__ float linv[32];

    const int tid = threadIdx.x;
    if (tid < 32) {
        float M = -1e30f;
        for (int c = 0; c < nact; ++c)
            M = fmaxf(M, Ml[(pbase + c) * 64 + tid]);
        float L = 0.f;
        for (int c = 0; c < nact; ++c) {
            float wv = exp2f(Ml[(pbase + c) * 64 + tid] - M);
            wgt[c][tid] = wv;
            L += wv * Ml[(pbase + c) * 64 + 32 + tid];
        }
        linv[tid] = 1.0f / L;
    }
    __syncthreads();

    const int d  = tid & 63;
    const int r0 = tid >> 6;
    for (int row = r0; row < 32; row += 4) {
        float a = 0.f;
        for (int c = 0; c < nact; ++c)
            a += wgt[c][row] * Op[(pbase + c) * 2048 + row * 64 + d];
        out[((size_t)b * T_SEQ + qt * 32 + row) * D_HEAD + d] = a * linv[row];
    }
}

extern "C" void kernel_launch(void* const* d_in, const int* in_sizes, int n_in,
                              void* d_out, int out_size, void* d_ws, size_t ws_size,
                              hipStream_t stream) {
    const float* x  = (const float*)d_in[0];
    const float* Wq = (const float*)d_in[1];
    const float* bq = (const float*)d_in[2];
    const float* Wk = (const float*)d_in[3];
    const float* bk = (const float*)d_in[4];
    const float* Wv = (const float*)d_in[5];
    const float* bv = (const float*)d_in[6];
    float* out = (float*)d_out;

    // workspace layout: q,k,v bf16 (1 MB each), Wp packed bf16 (786 KB), partials at +4 MB
    __hip_bfloat16* qb = (__hip_bfloat16*)d_ws;
    __hip_bfloat16* kb = qb + (size_t)NROWS * D_HEAD;
    __hip_bfloat16* vb = kb + (size_t)NROWS * D_HEAD;
    unsigned short* Wp = (unsigned short*)(vb + (size_t)NROWS * D_HEAD);
    float* Op = (float*)((char*)d_ws + (4u << 20));

    int nch = 8;
    while (nch > 1 &&
           (4u << 20) + (size_t)256 * nch * (2048 + 64) * 4 > ws_size)
        nch >>= 1;
    const int tpc = 64 / nch;
    float* Ml = Op + (size_t)256 * nch * 2048;

    wcvt_kernel<<<192, 256, 0, stream>>>(Wq, Wk, Wv, Wp);
    proj_mfma_kernel<<<NROWS / 32, 512, 0, stream>>>(x, Wp, bq, bk, bv, qb, kb, vb);
    attn_part_kernel<<<dim3(64, nch, B_SZ), 128, 0, stream>>>(qb, kb, vb, Op, Ml, tpc, nch);
    attn_combine_kernel<<<dim3(64, B_SZ), 256, 0, stream>>>(Op, Ml, out, tpc, nch);
}